// Round 5
// baseline (832.299 us; speedup 1.0000x reference)
//
#include <hip/hip_runtime.h>
#include <cmath>

#define NLEV 8
#define TSZ 16384
#define PRIME 2654435761u
#define NBINS 32   // V=20 actual; padded to 32

typedef float fx2 __attribute__((ext_vector_type(2)));

struct Res { int rx[NLEV]; int ry[NLEV]; };

// ---------------------------------------------------------------------------
// Shared per-point computation (hash-encode + MLP + heads + stores).
// `p` is the ORIGINAL point index (where outputs go); xv/hv are its data.
// ---------------------------------------------------------------------------
__device__ __forceinline__ void compute_point(
    fx2 xv, int hv, int p,
    const float* __restrict__ table,
    const float* __restrict__ w1, const float* __restrict__ b1,
    const float* __restrict__ w2, const float* __restrict__ b2,
    float* __restrict__ out, int N, const Res& res)
{
    const float* tb_base = table + (size_t)hv * (NLEV * TSZ * 2);

    float H[16];
    #pragma unroll
    for (int l = 0; l < NLEV; ++l) {
        float fx = (float)res.rx[l], fy = (float)res.ry[l];
        float posx = xv.x * fx, posy = xv.y * fy;
        float p0x = floorf(posx), p0y = floorf(posy);
        float wx = posx - p0x, wy = posy - p0y;
        unsigned cx = (unsigned)p0x, cy = (unsigned)p0y;
        const float* tb = tb_base + (size_t)l * (TSZ * 2);
        unsigned hy0 = cy * PRIME;
        unsigned hy1 = (cy + 1u) * PRIME;
        unsigned i00 = ( cx        ^ hy0) & (TSZ - 1);
        unsigned i10 = ((cx + 1u)  ^ hy0) & (TSZ - 1);
        unsigned i01 = ( cx        ^ hy1) & (TSZ - 1);
        unsigned i11 = ((cx + 1u)  ^ hy1) & (TSZ - 1);
        fx2 f00 = *(const fx2*)(tb + 2u * i00);
        fx2 f10 = *(const fx2*)(tb + 2u * i10);
        fx2 f01 = *(const fx2*)(tb + 2u * i01);
        fx2 f11 = *(const fx2*)(tb + 2u * i11);
        float w00 = (1.f - wx) * (1.f - wy);
        float w10 = wx * (1.f - wy);
        float w01 = (1.f - wx) * wy;
        float w11 = wx * wy;
        H[2*l]   = fmaf(f00.x, w00, fmaf(f10.x, w10, fmaf(f01.x, w01, f11.x * w11)));
        H[2*l+1] = fmaf(f00.y, w00, fmaf(f10.y, w10, fmaf(f01.y, w01, f11.y * w11)));
    }

    float h1[32];
    #pragma unroll
    for (int j = 0; j < 32; ++j) {
        float s = b1[j];
        #pragma unroll
        for (int k = 0; k < 16; ++k) s = fmaf(H[k], w1[k * 32 + j], s);
        h1[j] = __expf(-50.f * s * s);
    }

    float raw[24];
    #pragma unroll
    for (int j = 0; j < 24; ++j) {
        float s = b2[j];
        #pragma unroll
        for (int k = 0; k < 32; ++k) s = fmaf(h1[k], w2[k * 24 + j], s);
        raw[j] = s;
    }

    float wt[8], mu[8], isg[8];
    #pragma unroll
    for (int g = 0; g < 8; ++g) {
        wt[g]  = __expf(raw[g]);
        mu[g]  = 1.f / (1.f + __expf(-raw[8 + g]));
        isg[g] = __expf(raw[16 + g]);
    }

    size_t N8 = (size_t)N * 8;
    float4* o;
    o = (float4*)(out) + (size_t)p * 2;
    o[0] = make_float4(mu[0], mu[1], mu[2], mu[3]);
    o[1] = make_float4(mu[4], mu[5], mu[6], mu[7]);
    o = (float4*)(out + N8) + (size_t)p * 2;
    o[0] = make_float4(isg[0], isg[1], isg[2], isg[3]);
    o[1] = make_float4(isg[4], isg[5], isg[6], isg[7]);
    o = (float4*)(out + 2 * N8) + (size_t)p * 2;
    o[0] = make_float4(wt[0], wt[1], wt[2], wt[3]);
    o[1] = make_float4(wt[4], wt[5], wt[6], wt[7]);
    o = (float4*)(out + 3 * N8) + (size_t)p * 4;
    o[0] = make_float4(H[0],  H[1],  H[2],  H[3]);
    o[1] = make_float4(H[4],  H[5],  H[6],  H[7]);
    o[2] = make_float4(H[8],  H[9],  H[10], H[11]);
    o[3] = make_float4(H[12], H[13], H[14], H[15]);
}

// ---------------------------------------------------------------------------
// Fallback: original unsorted kernel (used when workspace is too small).
// ---------------------------------------------------------------------------
__global__ __launch_bounds__(256) void pg_kernel(
    const float* __restrict__ x, const int* __restrict__ hashidxs,
    const float* __restrict__ table,
    const float* __restrict__ w1, const float* __restrict__ b1,
    const float* __restrict__ w2, const float* __restrict__ b2,
    float* __restrict__ out, int N, Res res)
{
    int i = blockIdx.x * blockDim.x + threadIdx.x;
    if (i >= N) return;
    fx2 xv = ((const fx2*)x)[i];
    int hv = hashidxs[i];
    compute_point(xv, hv, i, table, w1, b1, w2, b2, out, N, res);
}

// ---------------------------------------------------------------------------
// Bucket-sort pipeline: zero -> hist -> scan -> scatter -> main.
// Rationale (round-4 finding): FETCH=1.03 GB vs 45 MB compulsory. The fine
// hash levels have a 10.5 MB hot random set vs 4 MB L2/XCD -> ~50% L2 miss on
// 33M 64B gathers = the 1 GB. Sorting by hv (V=20) + chunked XCD swizzle
// gives each XCD a ~2 MB slice -> L2-resident gathers.
// ---------------------------------------------------------------------------
__global__ void k_zero(int* __restrict__ c) {
    int t = threadIdx.x;
    if (t < 2 * NBINS) c[t] = 0;
}

__global__ __launch_bounds__(256) void k_hist(
    const int* __restrict__ hashidxs, int N, int* __restrict__ hist)
{
    __shared__ int lh[NBINS];
    int t = threadIdx.x;
    if (t < NBINS) lh[t] = 0;
    __syncthreads();
    int i = blockIdx.x * 256 + t;
    if (i < N) atomicAdd(&lh[hashidxs[i]], 1);
    __syncthreads();
    if (t < NBINS && lh[t]) atomicAdd(&hist[t], lh[t]);
}

__global__ void k_scan(const int* __restrict__ hist, int* __restrict__ cursor) {
    if (threadIdx.x == 0 && blockIdx.x == 0) {
        int acc = 0;
        for (int b = 0; b < NBINS; ++b) { cursor[b] = acc; acc += hist[b]; }
    }
}

__global__ __launch_bounds__(256) void k_scatter(
    const float* __restrict__ x, const int* __restrict__ hashidxs, int N,
    int* __restrict__ cursor, int* __restrict__ order, float* __restrict__ sx)
{
    __shared__ int lh[NBINS];
    __shared__ int lbase[NBINS];
    int t = threadIdx.x;
    if (t < NBINS) lh[t] = 0;
    __syncthreads();
    int i = blockIdx.x * 256 + t;
    int hv = -1, r = 0;
    if (i < N) { hv = hashidxs[i]; r = atomicAdd(&lh[hv], 1); }
    __syncthreads();
    if (t < NBINS && lh[t]) lbase[t] = atomicAdd(&cursor[t], lh[t]);
    __syncthreads();
    if (i < N) {
        int pos = lbase[hv] + r;
        order[pos] = i | (hv << 24);       // pack: i < 2^24, hv < 32
        ((fx2*)sx)[pos] = ((const fx2*)x)[i];
    }
}

__global__ __launch_bounds__(256) void pg_main(
    const int*   __restrict__ order,
    const float* __restrict__ sx,
    const float* __restrict__ table,
    const float* __restrict__ w1, const float* __restrict__ b1,
    const float* __restrict__ w2, const float* __restrict__ b2,
    float* __restrict__ out, int N, Res res)
{
    // Bijective chunked XCD swizzle (m204): HW assigns XCD = blockIdx % 8;
    // remap so each XCD gets a CONTIGUOUS range of the sorted point list ->
    // only ~2-3 hv slices per XCD L2 for the whole dispatch.
    unsigned nwg  = gridDim.x, orig = blockIdx.x;
    unsigned q = nwg / 8u, rr = nwg % 8u, xcd = orig % 8u;
    unsigned wg = (xcd < rr ? xcd * (q + 1u) : rr * (q + 1u) + (xcd - rr) * q) + orig / 8u;
    int j = (int)(wg * 256u + threadIdx.x);
    if (j >= N) return;

    int packed = order[j];
    int p  = packed & 0xFFFFFF;
    int hv = packed >> 24;
    fx2 xv = ((const fx2*)sx)[j];   // coalesced (sorted copy)
    compute_point(xv, hv, p, table, w1, b1, w2, b2, out, N, res);
}

extern "C" void kernel_launch(void* const* d_in, const int* in_sizes, int n_in,
                              void* d_out, int out_size, void* d_ws, size_t ws_size,
                              hipStream_t stream) {
    const float* x        = (const float*)d_in[0];
    const int*   hashidxs = (const int*)  d_in[1];
    // d_in[2] = color (unused by reference computation)
    const float* table    = (const float*)d_in[3];
    const float* w1       = (const float*)d_in[4];
    const float* b1       = (const float*)d_in[5];
    const float* w2       = (const float*)d_in[6];
    const float* b2       = (const float*)d_in[7];
    float* out = (float*)d_out;
    int N = in_sizes[0] / 2;

    // Replicate numpy's _level_resolutions() double-precision op sequence
    // exactly (floor(16*bx^7) sits ~3e-15 below 1024 — don't hardcode).
    Res res;
    double bx = std::exp((std::log((double)1024) - std::log((double)16)) / 7.0);
    double by = std::exp((std::log((double)768)  - std::log((double)16)) / 7.0);
    for (int l = 0; l < NLEV; ++l) {
        res.rx[l] = (int)std::floor(16.0 * std::pow(bx, (double)l));
        res.ry[l] = (int)std::floor(16.0 * std::pow(by, (double)l));
    }

    dim3 block(256);
    unsigned nwg = (unsigned)((N + 255) / 256);
    dim3 grid(nwg);

    // Workspace layout: [counters 2*NBINS ints | pad to 1KB | order N ints | sx N float2]
    size_t order_off = 1024;
    size_t sx_off    = order_off + (((size_t)N * 4 + 255) & ~(size_t)255);
    size_t ws_need   = sx_off + (size_t)N * 8;

    if (ws_size < ws_need || N >= (1 << 24)) {
        // Fallback: original unsorted kernel.
        hipLaunchKernelGGL(pg_kernel, grid, block, 0, stream,
                           x, hashidxs, table, w1, b1, w2, b2, out, N, res);
        return;
    }

    int*   hist   = (int*)d_ws;            // [0..NBINS)
    int*   cursor = (int*)d_ws + NBINS;    // [NBINS..2*NBINS)
    int*   order  = (int*)((char*)d_ws + order_off);
    float* sx     = (float*)((char*)d_ws + sx_off);

    hipLaunchKernelGGL(k_zero,    dim3(1),   dim3(64),  0, stream, hist);
    hipLaunchKernelGGL(k_hist,    grid,      block,     0, stream, hashidxs, N, hist);
    hipLaunchKernelGGL(k_scan,    dim3(1),   dim3(32),  0, stream, hist, cursor);
    hipLaunchKernelGGL(k_scatter, grid,      block,     0, stream, x, hashidxs, N, cursor, order, sx);
    hipLaunchKernelGGL(pg_main,   grid,      block,     0, stream,
                       order, sx, table, w1, b1, w2, b2, out, N, res);
}

// Round 6
// 831.499 us; speedup vs baseline: 1.0010x; 1.0010x over previous
//
#include <hip/hip_runtime.h>
#include <cmath>

#define NLEV 8
#define TSZ 16384
#define PRIME 2654435761u
#define CELLS 256           // 16x16 spatial cells per hv bin
#define MAXV 32             // packing limit: hv<<24, hv < 32

typedef float fx2 __attribute__((ext_vector_type(2)));

struct Res { int rx[NLEV]; int ry[NLEV]; };

// ---------------------------------------------------------------------------
// Shared per-point computation. MLP uses fx2 accumulators so the backend can
// select v_pk_fma_f32 (packed f32 FMA, 2 MACs/instr). Same op order as the
// scalar version -> bit-identical results.
// ---------------------------------------------------------------------------
__device__ __forceinline__ void compute_point(
    fx2 xv, int hv, int p,
    const float* __restrict__ table,
    const float* __restrict__ w1, const float* __restrict__ b1,
    const float* __restrict__ w2, const float* __restrict__ b2,
    float* __restrict__ out, int N, const Res& res)
{
    const float* tb_base = table + (size_t)hv * (NLEV * TSZ * 2);

    float H[16];
    #pragma unroll
    for (int l = 0; l < NLEV; ++l) {
        float fx = (float)res.rx[l], fy = (float)res.ry[l];
        float posx = xv.x * fx, posy = xv.y * fy;
        float p0x = floorf(posx), p0y = floorf(posy);
        float wx = posx - p0x, wy = posy - p0y;
        unsigned cx = (unsigned)p0x, cy = (unsigned)p0y;
        const float* tb = tb_base + (size_t)l * (TSZ * 2);
        unsigned hy0 = cy * PRIME;
        unsigned hy1 = (cy + 1u) * PRIME;
        unsigned i00 = ( cx        ^ hy0) & (TSZ - 1);
        unsigned i10 = ((cx + 1u)  ^ hy0) & (TSZ - 1);
        unsigned i01 = ( cx        ^ hy1) & (TSZ - 1);
        unsigned i11 = ((cx + 1u)  ^ hy1) & (TSZ - 1);
        fx2 f00 = *(const fx2*)(tb + 2u * i00);
        fx2 f10 = *(const fx2*)(tb + 2u * i10);
        fx2 f01 = *(const fx2*)(tb + 2u * i01);
        fx2 f11 = *(const fx2*)(tb + 2u * i11);
        float w00 = (1.f - wx) * (1.f - wy);
        float w10 = wx * (1.f - wy);
        float w01 = (1.f - wx) * wy;
        float w11 = wx * wy;
        H[2*l]   = fmaf(f00.x, w00, fmaf(f10.x, w10, fmaf(f01.x, w01, f11.x * w11)));
        H[2*l+1] = fmaf(f00.y, w00, fmaf(f10.y, w10, fmaf(f01.y, w01, f11.y * w11)));
    }

    // layer 1: 16 -> 32 (fx2-packed), gaussian activation exp(-50*s^2)
    fx2 acc1[16];
    #pragma unroll
    for (int j = 0; j < 16; ++j) acc1[j] = ((const fx2*)b1)[j];
    #pragma unroll
    for (int k = 0; k < 16; ++k) {
        fx2 hk = {H[k], H[k]};
        const fx2* wrow = (const fx2*)(w1 + k * 32);
        #pragma unroll
        for (int j = 0; j < 16; ++j)
            acc1[j] = __builtin_elementwise_fma(hk, wrow[j], acc1[j]);
    }
    float h1[32];
    #pragma unroll
    for (int j = 0; j < 16; ++j) {
        h1[2*j]   = __expf(-50.f * acc1[j].x * acc1[j].x);
        h1[2*j+1] = __expf(-50.f * acc1[j].y * acc1[j].y);
    }

    // layer 2: 32 -> 24 (fx2-packed)
    fx2 acc2[12];
    #pragma unroll
    for (int j = 0; j < 12; ++j) acc2[j] = ((const fx2*)b2)[j];
    #pragma unroll
    for (int k = 0; k < 32; ++k) {
        fx2 hk = {h1[k], h1[k]};
        const fx2* wrow = (const fx2*)(w2 + k * 24);
        #pragma unroll
        for (int j = 0; j < 12; ++j)
            acc2[j] = __builtin_elementwise_fma(hk, wrow[j], acc2[j]);
    }
    float raw[24];
    #pragma unroll
    for (int j = 0; j < 12; ++j) { raw[2*j] = acc2[j].x; raw[2*j+1] = acc2[j].y; }

    float wt[8], mu[8], isg[8];
    #pragma unroll
    for (int g = 0; g < 8; ++g) {
        wt[g]  = __expf(raw[g]);
        mu[g]  = 1.f / (1.f + __expf(-raw[8 + g]));
        isg[g] = __expf(raw[16 + g]);
    }

    size_t N8 = (size_t)N * 8;
    float4* o;
    o = (float4*)(out) + (size_t)p * 2;
    o[0] = make_float4(mu[0], mu[1], mu[2], mu[3]);
    o[1] = make_float4(mu[4], mu[5], mu[6], mu[7]);
    o = (float4*)(out + N8) + (size_t)p * 2;
    o[0] = make_float4(isg[0], isg[1], isg[2], isg[3]);
    o[1] = make_float4(isg[4], isg[5], isg[6], isg[7]);
    o = (float4*)(out + 2 * N8) + (size_t)p * 2;
    o[0] = make_float4(wt[0], wt[1], wt[2], wt[3]);
    o[1] = make_float4(wt[4], wt[5], wt[6], wt[7]);
    o = (float4*)(out + 3 * N8) + (size_t)p * 4;
    o[0] = make_float4(H[0],  H[1],  H[2],  H[3]);
    o[1] = make_float4(H[4],  H[5],  H[6],  H[7]);
    o[2] = make_float4(H[8],  H[9],  H[10], H[11]);
    o[3] = make_float4(H[12], H[13], H[14], H[15]);
}

// Fallback: original unsorted kernel.
__global__ __launch_bounds__(256) void pg_kernel(
    const float* __restrict__ x, const int* __restrict__ hashidxs,
    const float* __restrict__ table,
    const float* __restrict__ w1, const float* __restrict__ b1,
    const float* __restrict__ w2, const float* __restrict__ b2,
    float* __restrict__ out, int N, Res res)
{
    int i = blockIdx.x * blockDim.x + threadIdx.x;
    if (i >= N) return;
    fx2 xv = ((const fx2*)x)[i];
    int hv = hashidxs[i];
    compute_point(xv, hv, i, table, w1, b1, w2, b2, out, N, res);
}

// ---------------------------------------------------------------------------
// Sort pipeline. Round-5 result: hv-sort collapsed FETCH 1.03GB -> 26MB
// (table L2-resident). Round-6: add 16x16 spatial cell to the key so a wave's
// points span 1/16 x 1/16 of space -> levels 0-5 line footprint (<=19KB/run)
// becomes L1-resident; 5120 bins also kills LDS-atomic contention in
// hist/scatter (was 13-way on 20 bins).
// ---------------------------------------------------------------------------
__device__ __forceinline__ int spatial_bin(fx2 xv, int hv) {
    int gx = (int)(xv.x * 16.f); gx = gx > 15 ? 15 : gx;
    int gy = (int)(xv.y * 16.f); gy = gy > 15 ? 15 : gy;
    return hv * CELLS + gy * 16 + gx;
}

__global__ __launch_bounds__(256) void k_zero(int* __restrict__ c, int n) {
    int t = blockIdx.x * 256 + threadIdx.x;
    if (t < n) c[t] = 0;
}

__global__ __launch_bounds__(256) void k_hist(
    const float* __restrict__ x, const int* __restrict__ hashidxs, int N,
    int* __restrict__ hist, int NB)
{
    extern __shared__ int lh[];
    for (int b = threadIdx.x; b < NB; b += 256) lh[b] = 0;
    __syncthreads();
    int i = blockIdx.x * 256 + threadIdx.x;
    if (i < N) atomicAdd(&lh[spatial_bin(((const fx2*)x)[i], hashidxs[i])], 1);
    __syncthreads();
    for (int b = threadIdx.x; b < NB; b += 256) {
        int c = lh[b];
        if (c) atomicAdd(&hist[b], c);
    }
}

// Parallel exclusive scan over NB bins: 1 block, 256 threads.
// (Round-5 k_scan was 1 serial thread.)
__global__ __launch_bounds__(256) void k_scan(
    const int* __restrict__ hist, int* __restrict__ cursor, int NB)
{
    __shared__ int part[256];
    int t = threadIdx.x;
    const int BPT = 32;                 // supports NB <= 8192
    int loc[BPT];
    int base = t * ((NB + 255) / 256);
    int cnt  = (NB + 255) / 256;
    int s = 0;
    for (int b = 0; b < cnt; ++b) {
        int bin = base + b;
        loc[b] = s;
        if (bin < NB) s += hist[bin];
    }
    part[t] = s;
    __syncthreads();
    #pragma unroll
    for (int off = 1; off < 256; off <<= 1) {
        int v = (t >= off) ? part[t - off] : 0;
        __syncthreads();
        part[t] += v;
        __syncthreads();
    }
    int excl = (t == 0) ? 0 : part[t - 1];
    for (int b = 0; b < cnt; ++b) {
        int bin = base + b;
        if (bin < NB) cursor[bin] = excl + loc[b];
    }
}

__global__ __launch_bounds__(256) void k_scatter(
    const float* __restrict__ x, const int* __restrict__ hashidxs, int N,
    int* __restrict__ cursor, int* __restrict__ order, float* __restrict__ sx,
    int NB)
{
    extern __shared__ int sm[];
    int* lh    = sm;         // [NB]
    int* lbase = sm + NB;    // [NB]
    int t = threadIdx.x;
    for (int b = t; b < NB; b += 256) lh[b] = 0;
    __syncthreads();
    int i = blockIdx.x * 256 + t;
    int bin = -1, r = 0, hv = 0;
    fx2 xv;
    if (i < N) {
        hv = hashidxs[i];
        xv = ((const fx2*)x)[i];
        bin = spatial_bin(xv, hv);
        r = atomicAdd(&lh[bin], 1);
    }
    __syncthreads();
    for (int b = t; b < NB; b += 256) {
        int c = lh[b];
        if (c) lbase[b] = atomicAdd(&cursor[b], c);
    }
    __syncthreads();
    if (i < N) {
        int pos = lbase[bin] + r;
        order[pos] = i | (hv << 24);    // i < 2^24, hv < 32 (guarded on host)
        ((fx2*)sx)[pos] = xv;
    }
}

__global__ __launch_bounds__(256) void pg_main(
    const int*   __restrict__ order,
    const float* __restrict__ sx,
    const float* __restrict__ table,
    const float* __restrict__ w1, const float* __restrict__ b1,
    const float* __restrict__ w2, const float* __restrict__ b2,
    float* __restrict__ out, int N, Res res)
{
    // Bijective chunked XCD swizzle: each XCD gets a contiguous sorted range
    // -> ~2-3 hv table images (1MB each) per XCD L2.
    unsigned nwg  = gridDim.x, orig = blockIdx.x;
    unsigned q = nwg / 8u, rr = nwg % 8u, xcd = orig % 8u;
    unsigned wg = (xcd < rr ? xcd * (q + 1u) : rr * (q + 1u) + (xcd - rr) * q) + orig / 8u;
    int j = (int)(wg * 256u + threadIdx.x);
    if (j >= N) return;

    int packed = order[j];
    int p  = packed & 0xFFFFFF;
    int hv = packed >> 24;
    fx2 xv = ((const fx2*)sx)[j];   // coalesced (sorted copy)
    compute_point(xv, hv, p, table, w1, b1, w2, b2, out, N, res);
}

extern "C" void kernel_launch(void* const* d_in, const int* in_sizes, int n_in,
                              void* d_out, int out_size, void* d_ws, size_t ws_size,
                              hipStream_t stream) {
    const float* x        = (const float*)d_in[0];
    const int*   hashidxs = (const int*)  d_in[1];
    // d_in[2] = color (unused by reference computation)
    const float* table    = (const float*)d_in[3];
    const float* w1       = (const float*)d_in[4];
    const float* b1       = (const float*)d_in[5];
    const float* w2       = (const float*)d_in[6];
    const float* b2       = (const float*)d_in[7];
    float* out = (float*)d_out;
    int N = in_sizes[0] / 2;
    int V = in_sizes[3] / (NLEV * TSZ * 2);   // table float count -> V

    // Replicate numpy's _level_resolutions() double-precision op sequence
    // exactly (floor(16*bx^7) sits ~3e-15 below 1024 — don't hardcode).
    Res res;
    double bx = std::exp((std::log((double)1024) - std::log((double)16)) / 7.0);
    double by = std::exp((std::log((double)768)  - std::log((double)16)) / 7.0);
    for (int l = 0; l < NLEV; ++l) {
        res.rx[l] = (int)std::floor(16.0 * std::pow(bx, (double)l));
        res.ry[l] = (int)std::floor(16.0 * std::pow(by, (double)l));
    }

    dim3 block(256);
    unsigned nwg = (unsigned)((N + 255) / 256);
    dim3 grid(nwg);

    int NB = V * CELLS;
    // Workspace: [hist NB | cursor NB | pad to 256B | order N | sx N*2]
    size_t order_off = (((size_t)NB * 2 * 4) + 255) & ~(size_t)255;
    size_t sx_off    = order_off + (((size_t)N * 4 + 255) & ~(size_t)255);
    size_t ws_need   = sx_off + (size_t)N * 8;

    if (ws_size < ws_need || N >= (1 << 24) || V <= 0 || V > MAXV) {
        hipLaunchKernelGGL(pg_kernel, grid, block, 0, stream,
                           x, hashidxs, table, w1, b1, w2, b2, out, N, res);
        return;
    }

    int*   hist   = (int*)d_ws;
    int*   cursor = (int*)d_ws + NB;
    int*   order  = (int*)((char*)d_ws + order_off);
    float* sx     = (float*)((char*)d_ws + sx_off);

    size_t lds_h = (size_t)NB * 4;       // 20KB @ V=20
    size_t lds_s = (size_t)NB * 8;       // 40KB @ V=20

    hipLaunchKernelGGL(k_zero, dim3((NB + 255) / 256), block, 0, stream, hist, NB);
    hipLaunchKernelGGL(k_hist, grid, block, lds_h, stream, x, hashidxs, N, hist, NB);
    hipLaunchKernelGGL(k_scan, dim3(1), block, 0, stream, hist, cursor, NB);
    hipLaunchKernelGGL(k_scatter, grid, block, lds_s, stream,
                       x, hashidxs, N, cursor, order, sx, NB);
    hipLaunchKernelGGL(pg_main, grid, block, 0, stream,
                       order, sx, table, w1, b1, w2, b2, out, N, res);
}